// Round 19
// baseline (70.634 us; speedup 1.0000x reference)
//
#include <hip/hip_runtime.h>
#include <hip/hip_bf16.h>

// Problem constants (from reference)
#define NB      2048     // batch
#define RR      32       // rank per table
#define H_INIT  256
#define D_INIT  96
#define H_DYN   512
#define D_DYN   98
#define PCOLS   768      // H_INIT + H_DYN
#define NBLK    256      // grid size (1 block/CU)

#define LAM 2.8853900817779268f   // 2*log2(e): tanh(y) = 1 - 2/(exp2(LAM*y)+1)

typedef __attribute__((ext_vector_type(8))) short  short8;   // 8 bf16 (4 VGPRs)
typedef __attribute__((ext_vector_type(4))) float  f32x4;    // MFMA accum

__device__ __forceinline__ float fexp2(float x) {
#if __has_builtin(__builtin_amdgcn_exp2f)
    return __builtin_amdgcn_exp2f(x);
#else
    return exp2f(x);
#endif
}

// Wave64 sum -> uniform scalar. DPP row-scan + row_bcast; lands in lane 63.
// (proven rounds 1-18)
__device__ __forceinline__ float wave_total(float v) {
    v += __int_as_float(__builtin_amdgcn_update_dpp(0, __float_as_int(v), 0x111, 0xf, 0xf, false));
    v += __int_as_float(__builtin_amdgcn_update_dpp(0, __float_as_int(v), 0x112, 0xf, 0xf, false));
    v += __int_as_float(__builtin_amdgcn_update_dpp(0, __float_as_int(v), 0x114, 0xf, 0xf, false));
    v += __int_as_float(__builtin_amdgcn_update_dpp(0, __float_as_int(v), 0x118, 0xf, 0xf, false));
    v += __int_as_float(__builtin_amdgcn_update_dpp(0, __float_as_int(v), 0x142, 0xa, 0xf, false));
    v += __int_as_float(__builtin_amdgcn_update_dpp(0, __float_as_int(v), 0x143, 0xc, 0xf, false));
    return __int_as_float(__builtin_amdgcn_readlane(__float_as_int(v), 63));
}

// ---------------------------------------------------------------------------
// K_FUSED: one launch. Phase 1 = R13 k_gemm tile (frozen body). Homemade
// device-scope grid barrier (all 256 blocks guaranteed co-resident at
// 1 block/CU; >=2 fit by LDS/VGPR so residency is unconditional).
// Phase 2 = R17 k_rk4 body (frozen), 8 waves -> items [8b, 8b+8).
// cnt is memset to 0 before each launch (graph-capturable memset).
// ---------------------------------------------------------------------------
__global__ __launch_bounds__(512) void k_fused(
    const int* __restrict__ idx,
    const float* __restrict__ U0, const float* __restrict__ U1, const float* __restrict__ U2,
    const float* __restrict__ Wi1, const float* __restrict__ bi1,
    const float* __restrict__ Wd1, const float* __restrict__ bd1,
    const float* __restrict__ Wd2,
    const float* __restrict__ bt,
    const float* __restrict__ Wi2, const float* __restrict__ bi2,
    const float* __restrict__ bd2,
    float* __restrict__ P,
    float* __restrict__ At, float* __restrict__ Ct, float* __restrict__ W2m2t,
    unsigned* __restrict__ cnt,
    float* __restrict__ out)
{
    __shared__ __align__(16) ushort As[3 * 64 * 32];   // [ks][item][k] 12 KB
    __shared__ __align__(16) ushort Bs[3 * 96 * 32];   // [ks][unit][k] 18 KB
    __shared__ int idx_s[64 * 3];

    const int b   = blockIdx.x;            // 0..255
    const int tid = threadIdx.x;

    // ---- phase 0 (block 0 only): RK4-constant transpose, 1 j per thread ----
    if (b == 0) {
        const int j = tid;                 // 0..511
        At[j]    = LAM * Wd1[j * D_DYN + 0];
        Ct[j]    = LAM * Wd1[j * D_DYN + 1];
        W2m2t[j] = -2.f * Wd2[j];
    }

    // ================= phase 1: R13 GEMM tile (verbatim) =================
    const int ib    = b >> 3;              // 0..31 item tile
    const int jb    = b & 7;               // 0..7  unit tile
    const int item0 = ib * 64;
    const int unit0 = jb * 96;

    if (tid < 192) idx_s[tid] = idx[item0 * 3 + tid];
    __syncthreads();

    // ---- A stage: 3072 float2 -> 6 per thread ----
    #pragma unroll
    for (int p = 0; p < 6; ++p) {
        int e2  = tid + 512 * p;
        int ks  = e2 >> 10;
        int rem = e2 & 1023;
        int i   = rem >> 4, m = rem & 15;
        const float* __restrict__ U = (ks == 0) ? U0 : (ks == 1) ? U1 : U2;
        float2 v = *(const float2*)&U[idx_s[i * 3 + ks] * RR + 2 * m];
        *(__hip_bfloat162*)&As[ks * 2048 + i * 32 + 2 * m] = __float22bfloat162_rn(v);
    }
    // ---- B stage: 4608 float2 -> 9 per thread (panel stride 3072) ----
    #pragma unroll
    for (int p = 0; p < 9; ++p) {
        int e2  = tid + 512 * p;
        int ks  = e2 / 1536;
        int rem = e2 - ks * 1536;
        int j   = rem >> 4, m = rem & 15;
        int gu  = unit0 + j;
        const float* __restrict__ src = (gu < H_INIT)
            ? &Wi1[gu * D_INIT + ks * 32 + 2 * m]
            : &Wd1[(gu - H_INIT) * D_DYN + 2 + ks * 32 + 2 * m];
        float2 v = *(const float2*)src;
        *(__hip_bfloat162*)&Bs[ks * 3072 + j * 32 + 2 * m] = __float22bfloat162_rn(v);
    }
    __syncthreads();

    // ---- MFMA: wave (mw,nw) -> 16 items x 48 units ----
    const int lane  = tid & 63;
    const int w     = tid >> 6;            // 0..7
    const int mw    = w >> 1;              // 0..3
    const int nw    = w & 1;               // 0..1
    const int frow  = lane & 15;
    const int koff8 = (lane >> 4) * 8;

    {
        short8 afr[3];
        #pragma unroll
        for (int ks = 0; ks < 3; ++ks)
            afr[ks] = *(const short8*)&As[ks * 2048 + (mw * 16 + frow) * 32 + koff8];

        f32x4 acc[3];
        #pragma unroll
        for (int nt = 0; nt < 3; ++nt) acc[nt] = (f32x4){0.f, 0.f, 0.f, 0.f};
        #pragma unroll
        for (int nt = 0; nt < 3; ++nt) {
            const int brow = nw * 48 + nt * 16 + frow;
            #pragma unroll
            for (int ks = 0; ks < 3; ++ks) {
                short8 bfr = *(const short8*)&Bs[ks * 3072 + brow * 32 + koff8];
                acc[nt] = __builtin_amdgcn_mfma_f32_16x16x32_bf16(afr[ks], bfr, acc[nt], 0, 0, 0);
            }
        }

        // ---- epilogue: C/D col = lane&15, row = (lane>>4)*4 + r ----
        const int rbase = (lane >> 4) * 4;
        #pragma unroll
        for (int nt = 0; nt < 3; ++nt) {
            const int gu = unit0 + nw * 48 + nt * 16 + frow;
            const float bias = (gu < H_INIT) ? bi1[gu] : bd1[gu - H_INIT];
            #pragma unroll
            for (int r = 0; r < 4; ++r) {
                const int item = item0 + mw * 16 + rbase + r;
                P[item * PCOLS + gu] = LAM * (acc[nt][r] + bias);
            }
        }
    }

    // ================= grid barrier (device-scope) =================
    __syncthreads();                       // all P stores issued block-wide
    if (tid == 0) {
        __threadfence();                   // release: drain + make P device-visible
        atomicAdd(cnt, 1u);
        while (atomicAdd(cnt, 0u) < NBLK)  // coherent read via atomic
            __builtin_amdgcn_s_sleep(2);
    }
    __syncthreads();
    __threadfence();                       // acquire: kill stale lines (prev replay)

    // ================= phase 2: R17 RK4-2 body (verbatim) =================
    const int item = b * 8 + w;

    const float* __restrict__ Prow = P + item * PCOLS;
    const float s = bt[item];

    float a[8], c[8], w2m2[8], g[8];
    float w2p = 0.f;
    #pragma unroll
    for (int u = 0; u < 8; ++u) {
        int j = u * 64 + lane;
        a[u]    = s * At[j];               // == (LAM*s)*Wd1[j][0]
        c[u]    = Ct[j];
        w2m2[u] = W2m2t[j];
        w2p    += -0.5f * w2m2[u];         // == Wd2[j], exact
        g[u]    = Prow[H_INIT + j];
    }
    const float W2sum = wave_total(w2p);
    const float Kc    = W2sum + bd2[0];    // folded  sum(w2) + bd2

    // init MLP: x0 = sum_j Wi2[j] * tanh(yj) + bi2
    float acc0 = 0.f, acc1 = 0.f;
    #pragma unroll
    for (int q = 0; q < 4; ++q) {
        int j = q * 64 + lane;
        float e = fexp2(Prow[j]);                     // already LAM*(pre+bias)
        float r = __builtin_amdgcn_rcpf(e + 1.f);
        float t = fmaf(-2.f, r, 1.f);
        if (q & 1) acc1 = fmaf(Wi2[j], t, acc1);
        else       acc0 = fmaf(Wi2[j], t, acc0);
    }
    float x = wave_total(acc0 + acc1) + bi2[0];

    auto feval = [&](float tt, float xv) -> float {
        float accp0 = 0.f, accp1 = 0.f;
        #pragma unroll
        for (int u = 0; u < 8; ++u) {
            float y2 = fmaf(a[u], tt, fmaf(c[u], xv, g[u]));
            float e  = fexp2(y2);
            float r  = __builtin_amdgcn_rcpf(e + 1.f);
            if (u & 1) accp1 = fmaf(w2m2[u], r, accp1);
            else       accp0 = fmaf(w2m2[u], r, accp0);
        }
        return (wave_total(accp0 + accp1) + Kc) * s;
    };

    const float H  = 0.5f;
    const float H2 = 0.25f;
    #pragma unroll
    for (int i = 0; i < 2; ++i) {
        float t   = (float)i * H;   // literal after unroll
        float k1v = feval(t,      x);
        float k2v = feval(t + H2, fmaf(H2, k1v, x));
        float k3v = feval(t + H2, fmaf(H2, k2v, x));
        float k4v = feval(t + H,  fmaf(H, k3v, x));
        x = x + (H / 6.f) * (k1v + 2.f * (k2v + k3v) + k4v);
    }

    if (lane == 0) out[item] = x;
}

extern "C" void kernel_launch(void* const* d_in, const int* in_sizes, int n_in,
                              void* d_out, int out_size, void* d_ws, size_t ws_size,
                              hipStream_t stream) {
    const int*   b_i_n = (const int*)d_in[0];
    const float* b_t_n = (const float*)d_in[1];
    const float* U0    = (const float*)d_in[2];
    const float* U1    = (const float*)d_in[3];
    const float* U2    = (const float*)d_in[4];
    const float* Wi1   = (const float*)d_in[5];
    const float* bi1   = (const float*)d_in[6];
    const float* Wi2   = (const float*)d_in[7];
    const float* bi2   = (const float*)d_in[8];
    const float* Wd1   = (const float*)d_in[9];
    const float* bd1   = (const float*)d_in[10];
    const float* Wd2   = (const float*)d_in[11];
    const float* bd2   = (const float*)d_in[12];
    float* outp = (float*)d_out;

    char* ws = (char*)d_ws;
    float*    P     = (float*)ws;                     // 6291456 B
    float*    At    = (float*)(ws + 6291456);         // 2048 B
    float*    Ct    = (float*)(ws + 6293504);         // 2048 B
    float*    W2m2t = (float*)(ws + 6295552);         // 2048 B
    unsigned* cnt   = (unsigned*)(ws + 6297600);      // 4 B barrier counter

    hipMemsetAsync(cnt, 0, 4, stream);                // deterministic per call
    k_fused<<<NBLK, 512, 0, stream>>>(b_i_n, U0, U1, U2, Wi1, bi1, Wd1, bd1,
                                      Wd2, b_t_n, Wi2, bi2, bd2,
                                      P, At, Ct, W2m2t, cnt, outp);
}

// Round 20
// 16.682 us; speedup vs baseline: 4.2340x; 4.2340x over previous
//
#include <hip/hip_runtime.h>
#include <hip/hip_bf16.h>

// Problem constants (from reference)
#define NB      2048     // batch
#define RR      32       // rank per table
#define H_INIT  256
#define D_INIT  96
#define H_DYN   512
#define D_DYN   98
#define PCOLS   768      // H_INIT + H_DYN

#define LAM 2.8853900817779268f   // 2*log2(e): tanh(y) = 1 - 2/(exp2(LAM*y)+1)

typedef __attribute__((ext_vector_type(8))) short  short8;   // 8 bf16 (4 VGPRs)
typedef __attribute__((ext_vector_type(4))) float  f32x4;    // MFMA accum

__device__ __forceinline__ float fexp2(float x) {
#if __has_builtin(__builtin_amdgcn_exp2f)
    return __builtin_amdgcn_exp2f(x);
#else
    return exp2f(x);
#endif
}

// Wave64 sum -> uniform scalar. DPP row-scan + row_bcast; lands in lane 63.
// (proven rounds 1-19)
__device__ __forceinline__ float wave_total(float v) {
    v += __int_as_float(__builtin_amdgcn_update_dpp(0, __float_as_int(v), 0x111, 0xf, 0xf, false));
    v += __int_as_float(__builtin_amdgcn_update_dpp(0, __float_as_int(v), 0x112, 0xf, 0xf, false));
    v += __int_as_float(__builtin_amdgcn_update_dpp(0, __float_as_int(v), 0x114, 0xf, 0xf, false));
    v += __int_as_float(__builtin_amdgcn_update_dpp(0, __float_as_int(v), 0x118, 0xf, 0xf, false));
    v += __int_as_float(__builtin_amdgcn_update_dpp(0, __float_as_int(v), 0x142, 0xa, 0xf, false));
    v += __int_as_float(__builtin_amdgcn_update_dpp(0, __float_as_int(v), 0x143, 0xc, 0xf, false));
    return __int_as_float(__builtin_amdgcn_readlane(__float_as_int(v), 63));
}

// RN bf16 pack, identical rounding path to all prior rounds.
__device__ __forceinline__ short8 pack_bf16x8(float4 lo, float4 hi) {
    union { short8 s; __hip_bfloat162 h[4]; } u;
    u.h[0] = __float22bfloat162_rn({lo.x, lo.y});
    u.h[1] = __float22bfloat162_rn({lo.z, lo.w});
    u.h[2] = __float22bfloat162_rn({hi.x, hi.y});
    u.h[3] = __float22bfloat162_rn({hi.z, hi.w});
    return u.s;
}

// ---------------------------------------------------------------------------
// K_GEMM (A-direct): R13 tile/wave layout, but A-fragments load STRAIGHT
// from the U tables into registers (R8/R10/R14-proven path) — removes the
// idx_s stage, the A-LDS round-trip, and one barrier. The 6 gather loads
// per lane issue before the B-stage and drain during it. B stays in LDS
// (R14 showed B-streaming regresses). Numerics bit-identical to R13-R18.
// Grid 257: blocks 0..255 = 64-item x 96-unit tiles; block 256 = constants.
// ---------------------------------------------------------------------------
__global__ __launch_bounds__(512) void k_gemm(
    const int* __restrict__ idx,
    const float* __restrict__ U0, const float* __restrict__ U1, const float* __restrict__ U2,
    const float* __restrict__ Wi1, const float* __restrict__ bi1,
    const float* __restrict__ Wd1, const float* __restrict__ bd1,
    const float* __restrict__ Wd2,
    float* __restrict__ P,
    float* __restrict__ At, float* __restrict__ Ct, float* __restrict__ W2m2t)
{
    const int b   = blockIdx.x;
    const int tid = threadIdx.x;

    if (b == 256) {                        // RK4-constant transpose block
        const int j = tid;                 // 0..511
        At[j]    = LAM * Wd1[j * D_DYN + 0];
        Ct[j]    = LAM * Wd1[j * D_DYN + 1];
        W2m2t[j] = -2.f * Wd2[j];
        return;
    }

    __shared__ __align__(16) ushort Bs[3 * 96 * 32];   // [ks][unit][k] 18 KB

    const int ib    = b >> 3;              // 0..31 item tile
    const int jb    = b & 7;               // 0..7  unit tile
    const int item0 = ib * 64;
    const int unit0 = jb * 96;

    const int lane  = tid & 63;
    const int w     = tid >> 6;            // 0..7
    const int mw    = w >> 1;              // 0..3
    const int nw    = w & 1;               // 0..1
    const int frow  = lane & 15;
    const int koff8 = (lane >> 4) * 8;

    // ---- A fragments direct from U (issue first; drain under B-stage) ----
    const int ia = item0 + mw * 16 + frow;       // all 16 rows real
    short8 afr[3];
    #pragma unroll
    for (int ks = 0; ks < 3; ++ks) {
        const float* __restrict__ Ut = (ks == 0) ? U0 : (ks == 1) ? U1 : U2;
        const int iv = idx[ia * 3 + ks];
        float4 f0 = *(const float4*)&Ut[iv * RR + koff8];
        float4 f1 = *(const float4*)&Ut[iv * RR + koff8 + 4];
        afr[ks] = pack_bf16x8(f0, f1);
    }

    // ---- B stage: 4608 float2 -> 9 per thread (R13 verbatim) ----
    #pragma unroll
    for (int p = 0; p < 9; ++p) {
        int e2  = tid + 512 * p;
        int ks  = e2 / 1536;
        int rem = e2 - ks * 1536;
        int j   = rem >> 4, m = rem & 15;
        int gu  = unit0 + j;
        const float* __restrict__ src = (gu < H_INIT)
            ? &Wi1[gu * D_INIT + ks * 32 + 2 * m]
            : &Wd1[(gu - H_INIT) * D_DYN + 2 + ks * 32 + 2 * m];
        float2 v = *(const float2*)src;
        *(__hip_bfloat162*)&Bs[ks * 3072 + j * 32 + 2 * m] = __float22bfloat162_rn(v);
    }
    __syncthreads();

    // ---- MFMA: wave (mw,nw) -> 16 items x 48 units ----
    f32x4 acc[3];
    #pragma unroll
    for (int nt = 0; nt < 3; ++nt) acc[nt] = (f32x4){0.f, 0.f, 0.f, 0.f};
    #pragma unroll
    for (int nt = 0; nt < 3; ++nt) {
        const int brow = nw * 48 + nt * 16 + frow;
        #pragma unroll
        for (int ks = 0; ks < 3; ++ks) {
            short8 bfr = *(const short8*)&Bs[ks * 3072 + brow * 32 + koff8];
            acc[nt] = __builtin_amdgcn_mfma_f32_16x16x32_bf16(afr[ks], bfr, acc[nt], 0, 0, 0);
        }
    }

    // ---- epilogue: C/D col = lane&15, row = (lane>>4)*4 + r ----
    const int rbase = (lane >> 4) * 4;
    #pragma unroll
    for (int nt = 0; nt < 3; ++nt) {
        const int gu = unit0 + nw * 48 + nt * 16 + frow;
        const float bias = (gu < H_INIT) ? bi1[gu] : bd1[gu - H_INIT];
        #pragma unroll
        for (int r = 0; r < 4; ++r) {
            const int item = item0 + mw * 16 + rbase + r;
            P[item * PCOLS + gu] = LAM * (acc[nt][r] + bias);
        }
    }
}

// ---------------------------------------------------------------------------
// K_RK4: R17 VERBATIM — one wave per item, RK4-2 (8 evals). ILP-2 (R18) and
// team-split (R16) both failed to beat it; frozen.
// ---------------------------------------------------------------------------
__global__ __launch_bounds__(256) void k_rk4(
    const float* __restrict__ bt,
    const float* __restrict__ At, const float* __restrict__ Ct,
    const float* __restrict__ W2m2t,
    const float* __restrict__ Wi2, const float* __restrict__ bi2,
    const float* __restrict__ bd2,
    const float* __restrict__ P,
    float* __restrict__ out)
{
    const int lane = threadIdx.x & 63;
    const int wv   = threadIdx.x >> 6;
    const int item = blockIdx.x * 4 + wv;

    const float* __restrict__ Prow = P + item * PCOLS;
    const float s = bt[item];

    float a[8], c[8], w2m2[8], g[8];
    float w2p = 0.f;
    #pragma unroll
    for (int u = 0; u < 8; ++u) {
        int j = u * 64 + lane;
        a[u]    = s * At[j];               // == (LAM*s)*Wd1[j][0]
        c[u]    = Ct[j];
        w2m2[u] = W2m2t[j];
        w2p    += -0.5f * w2m2[u];         // == Wd2[j], exact
        g[u]    = Prow[H_INIT + j];
    }
    const float W2sum = wave_total(w2p);
    const float Kc    = W2sum + bd2[0];    // folded  sum(w2) + bd2

    // init MLP: x0 = sum_j Wi2[j] * tanh(yj) + bi2
    float acc0 = 0.f, acc1 = 0.f;
    #pragma unroll
    for (int q = 0; q < 4; ++q) {
        int j = q * 64 + lane;
        float e = fexp2(Prow[j]);                     // already LAM*(pre+bias)
        float r = __builtin_amdgcn_rcpf(e + 1.f);
        float t = fmaf(-2.f, r, 1.f);
        if (q & 1) acc1 = fmaf(Wi2[j], t, acc1);
        else       acc0 = fmaf(Wi2[j], t, acc0);
    }
    float x = wave_total(acc0 + acc1) + bi2[0];

    auto feval = [&](float tt, float xv) -> float {
        float accp0 = 0.f, accp1 = 0.f;
        #pragma unroll
        for (int u = 0; u < 8; ++u) {
            float y2 = fmaf(a[u], tt, fmaf(c[u], xv, g[u]));
            float e  = fexp2(y2);
            float r  = __builtin_amdgcn_rcpf(e + 1.f);
            if (u & 1) accp1 = fmaf(w2m2[u], r, accp1);
            else       accp0 = fmaf(w2m2[u], r, accp0);
        }
        return (wave_total(accp0 + accp1) + Kc) * s;
    };

    const float H  = 0.5f;
    const float H2 = 0.25f;
    #pragma unroll
    for (int i = 0; i < 2; ++i) {
        float t   = (float)i * H;   // literal after unroll
        float k1v = feval(t,      x);
        float k2v = feval(t + H2, fmaf(H2, k1v, x));
        float k3v = feval(t + H2, fmaf(H2, k2v, x));
        float k4v = feval(t + H,  fmaf(H, k3v, x));
        x = x + (H / 6.f) * (k1v + 2.f * (k2v + k3v) + k4v);
    }

    if (lane == 0) out[item] = x;
}

extern "C" void kernel_launch(void* const* d_in, const int* in_sizes, int n_in,
                              void* d_out, int out_size, void* d_ws, size_t ws_size,
                              hipStream_t stream) {
    const int*   b_i_n = (const int*)d_in[0];
    const float* b_t_n = (const float*)d_in[1];
    const float* U0    = (const float*)d_in[2];
    const float* U1    = (const float*)d_in[3];
    const float* U2    = (const float*)d_in[4];
    const float* Wi1   = (const float*)d_in[5];
    const float* bi1   = (const float*)d_in[6];
    const float* Wi2   = (const float*)d_in[7];
    const float* bi2   = (const float*)d_in[8];
    const float* Wd1   = (const float*)d_in[9];
    const float* bd1   = (const float*)d_in[10];
    const float* Wd2   = (const float*)d_in[11];
    const float* bd2   = (const float*)d_in[12];
    float* outp = (float*)d_out;

    char* ws = (char*)d_ws;
    float* P     = (float*)ws;                        // 6291456 B
    float* At    = (float*)(ws + 6291456);            // 2048 B
    float* Ct    = (float*)(ws + 6293504);            // 2048 B
    float* W2m2t = (float*)(ws + 6295552);            // 2048 B

    k_gemm<<<257, 512, 0, stream>>>(b_i_n, U0, U1, U2, Wi1, bi1, Wd1, bd1, Wd2,
                                    P, At, Ct, W2m2t);
    k_rk4<<<NB / 4, 256, 0, stream>>>(b_t_n, At, Ct, W2m2t, Wi2, bi2, bd2,
                                      P, outp);
}

// Round 21
// 16.046 us; speedup vs baseline: 4.4019x; 1.0396x over previous
//
#include <hip/hip_runtime.h>
#include <hip/hip_bf16.h>

// Problem constants (from reference)
#define NB      2048     // batch
#define RR      32       // rank per table
#define H_INIT  256
#define D_INIT  96
#define H_DYN   512
#define D_DYN   98
#define PCOLS   768      // H_INIT + H_DYN

#define LAM 2.8853900817779268f   // 2*log2(e): tanh(y) = 1 - 2/(exp2(LAM*y)+1)

typedef __attribute__((ext_vector_type(8))) short  short8;   // 8 bf16 (4 VGPRs)
typedef __attribute__((ext_vector_type(4))) float  f32x4;    // MFMA accum

__device__ __forceinline__ float fexp2(float x) {
#if __has_builtin(__builtin_amdgcn_exp2f)
    return __builtin_amdgcn_exp2f(x);
#else
    return exp2f(x);
#endif
}

// Wave64 sum -> uniform scalar. DPP row-scan + row_bcast; lands in lane 63.
// (proven rounds 1-20)
__device__ __forceinline__ float wave_total(float v) {
    v += __int_as_float(__builtin_amdgcn_update_dpp(0, __float_as_int(v), 0x111, 0xf, 0xf, false));
    v += __int_as_float(__builtin_amdgcn_update_dpp(0, __float_as_int(v), 0x112, 0xf, 0xf, false));
    v += __int_as_float(__builtin_amdgcn_update_dpp(0, __float_as_int(v), 0x114, 0xf, 0xf, false));
    v += __int_as_float(__builtin_amdgcn_update_dpp(0, __float_as_int(v), 0x118, 0xf, 0xf, false));
    v += __int_as_float(__builtin_amdgcn_update_dpp(0, __float_as_int(v), 0x142, 0xa, 0xf, false));
    v += __int_as_float(__builtin_amdgcn_update_dpp(0, __float_as_int(v), 0x143, 0xc, 0xf, false));
    return __int_as_float(__builtin_amdgcn_readlane(__float_as_int(v), 63));
}

// ---------------------------------------------------------------------------
// K_GEMM: R13 VERBATIM — frozen. Every variant regressed:
//   R14 B-stream (+1.7), R15 32x96 retile (+1.2), R20 A-direct (+0.85).
// 64-item x 96-unit tiles, 512 threads, convert-during-stage, 9 MFMA/wave.
// Block 256 builds pre-transposed RK4 constants.
// ---------------------------------------------------------------------------
__global__ __launch_bounds__(512) void k_gemm(
    const int* __restrict__ idx,
    const float* __restrict__ U0, const float* __restrict__ U1, const float* __restrict__ U2,
    const float* __restrict__ Wi1, const float* __restrict__ bi1,
    const float* __restrict__ Wd1, const float* __restrict__ bd1,
    const float* __restrict__ Wd2,
    float* __restrict__ P,
    float* __restrict__ At, float* __restrict__ Ct, float* __restrict__ W2m2t)
{
    const int b   = blockIdx.x;
    const int tid = threadIdx.x;

    if (b == 256) {                        // RK4-constant transpose block
        const int j = tid;                 // 0..511
        At[j]    = LAM * Wd1[j * D_DYN + 0];
        Ct[j]    = LAM * Wd1[j * D_DYN + 1];
        W2m2t[j] = -2.f * Wd2[j];
        return;
    }

    __shared__ __align__(16) ushort As[3 * 64 * 32];   // [ks][item][k] 12 KB
    __shared__ __align__(16) ushort Bs[3 * 96 * 32];   // [ks][unit][k] 18 KB
    __shared__ int idx_s[64 * 3];

    const int ib    = b >> 3;              // 0..31 item tile
    const int jb    = b & 7;               // 0..7  unit tile
    const int item0 = ib * 64;
    const int unit0 = jb * 96;

    if (tid < 192) idx_s[tid] = idx[item0 * 3 + tid];
    __syncthreads();

    // ---- A stage: 3072 float2 -> 6 per thread ----
    #pragma unroll
    for (int p = 0; p < 6; ++p) {
        int e2  = tid + 512 * p;
        int ks  = e2 >> 10;
        int rem = e2 & 1023;
        int i   = rem >> 4, m = rem & 15;
        const float* __restrict__ U = (ks == 0) ? U0 : (ks == 1) ? U1 : U2;
        float2 v = *(const float2*)&U[idx_s[i * 3 + ks] * RR + 2 * m];
        *(__hip_bfloat162*)&As[ks * 2048 + i * 32 + 2 * m] = __float22bfloat162_rn(v);
    }
    // ---- B stage: 4608 float2 -> 9 per thread (panel stride 3072) ----
    #pragma unroll
    for (int p = 0; p < 9; ++p) {
        int e2  = tid + 512 * p;
        int ks  = e2 / 1536;
        int rem = e2 - ks * 1536;
        int j   = rem >> 4, m = rem & 15;
        int gu  = unit0 + j;
        const float* __restrict__ src = (gu < H_INIT)
            ? &Wi1[gu * D_INIT + ks * 32 + 2 * m]
            : &Wd1[(gu - H_INIT) * D_DYN + 2 + ks * 32 + 2 * m];
        float2 v = *(const float2*)src;
        *(__hip_bfloat162*)&Bs[ks * 3072 + j * 32 + 2 * m] = __float22bfloat162_rn(v);
    }
    __syncthreads();

    // ---- MFMA: wave (mw,nw) -> 16 items x 48 units ----
    const int lane  = tid & 63;
    const int w     = tid >> 6;
    const int mw    = w >> 1;              // 0..3
    const int nw    = w & 1;               // 0..1
    const int frow  = lane & 15;
    const int koff8 = (lane >> 4) * 8;

    short8 afr[3];
    #pragma unroll
    for (int ks = 0; ks < 3; ++ks)
        afr[ks] = *(const short8*)&As[ks * 2048 + (mw * 16 + frow) * 32 + koff8];

    f32x4 acc[3];
    #pragma unroll
    for (int nt = 0; nt < 3; ++nt) acc[nt] = (f32x4){0.f, 0.f, 0.f, 0.f};
    #pragma unroll
    for (int nt = 0; nt < 3; ++nt) {
        const int brow = nw * 48 + nt * 16 + frow;
        #pragma unroll
        for (int ks = 0; ks < 3; ++ks) {
            short8 bfr = *(const short8*)&Bs[ks * 3072 + brow * 32 + koff8];
            acc[nt] = __builtin_amdgcn_mfma_f32_16x16x32_bf16(afr[ks], bfr, acc[nt], 0, 0, 0);
        }
    }

    // ---- epilogue: C/D col = lane&15, row = (lane>>4)*4 + r ----
    const int rbase = (lane >> 4) * 4;
    #pragma unroll
    for (int nt = 0; nt < 3; ++nt) {
        const int gu = unit0 + nw * 48 + nt * 16 + frow;
        const float bias = (gu < H_INIT) ? bi1[gu] : bd1[gu - H_INIT];
        #pragma unroll
        for (int r = 0; r < 4; ++r) {
            const int item = item0 + mw * 16 + rbase + r;
            P[item * PCOLS + gu] = LAM * (acc[nt][r] + bias);
        }
    }
}

// ---------------------------------------------------------------------------
// K_RK4: R17 VERBATIM — one wave per item, RK4-2 (8 evals). Frozen:
// team-split (R16), ILP-2 (R18) regressed/null. Error budget measured:
// absmax bit-identical 0.00390625 through RK4-4/3/2 -> integrator error
// still below half a bf16 output ulp; RK4-1 would break the threshold.
// ---------------------------------------------------------------------------
__global__ __launch_bounds__(256) void k_rk4(
    const float* __restrict__ bt,
    const float* __restrict__ At, const float* __restrict__ Ct,
    const float* __restrict__ W2m2t,
    const float* __restrict__ Wi2, const float* __restrict__ bi2,
    const float* __restrict__ bd2,
    const float* __restrict__ P,
    float* __restrict__ out)
{
    const int lane = threadIdx.x & 63;
    const int wv   = threadIdx.x >> 6;
    const int item = blockIdx.x * 4 + wv;

    const float* __restrict__ Prow = P + item * PCOLS;
    const float s = bt[item];

    float a[8], c[8], w2m2[8], g[8];
    float w2p = 0.f;
    #pragma unroll
    for (int u = 0; u < 8; ++u) {
        int j = u * 64 + lane;
        a[u]    = s * At[j];               // == (LAM*s)*Wd1[j][0]
        c[u]    = Ct[j];
        w2m2[u] = W2m2t[j];
        w2p    += -0.5f * w2m2[u];         // == Wd2[j], exact
        g[u]    = Prow[H_INIT + j];
    }
    const float W2sum = wave_total(w2p);
    const float Kc    = W2sum + bd2[0];    // folded  sum(w2) + bd2

    // init MLP: x0 = sum_j Wi2[j] * tanh(yj) + bi2
    float acc0 = 0.f, acc1 = 0.f;
    #pragma unroll
    for (int q = 0; q < 4; ++q) {
        int j = q * 64 + lane;
        float e = fexp2(Prow[j]);                     // already LAM*(pre+bias)
        float r = __builtin_amdgcn_rcpf(e + 1.f);
        float t = fmaf(-2.f, r, 1.f);
        if (q & 1) acc1 = fmaf(Wi2[j], t, acc1);
        else       acc0 = fmaf(Wi2[j], t, acc0);
    }
    float x = wave_total(acc0 + acc1) + bi2[0];

    auto feval = [&](float tt, float xv) -> float {
        float accp0 = 0.f, accp1 = 0.f;
        #pragma unroll
        for (int u = 0; u < 8; ++u) {
            float y2 = fmaf(a[u], tt, fmaf(c[u], xv, g[u]));
            float e  = fexp2(y2);
            float r  = __builtin_amdgcn_rcpf(e + 1.f);
            if (u & 1) accp1 = fmaf(w2m2[u], r, accp1);
            else       accp0 = fmaf(w2m2[u], r, accp0);
        }
        return (wave_total(accp0 + accp1) + Kc) * s;
    };

    const float H  = 0.5f;
    const float H2 = 0.25f;
    #pragma unroll
    for (int i = 0; i < 2; ++i) {
        float t   = (float)i * H;   // literal after unroll
        float k1v = feval(t,      x);
        float k2v = feval(t + H2, fmaf(H2, k1v, x));
        float k3v = feval(t + H2, fmaf(H2, k2v, x));
        float k4v = feval(t + H,  fmaf(H, k3v, x));
        x = x + (H / 6.f) * (k1v + 2.f * (k2v + k3v) + k4v);
    }

    if (lane == 0) out[item] = x;
}

extern "C" void kernel_launch(void* const* d_in, const int* in_sizes, int n_in,
                              void* d_out, int out_size, void* d_ws, size_t ws_size,
                              hipStream_t stream) {
    const int*   b_i_n = (const int*)d_in[0];
    const float* b_t_n = (const float*)d_in[1];
    const float* U0    = (const float*)d_in[2];
    const float* U1    = (const float*)d_in[3];
    const float* U2    = (const float*)d_in[4];
    const float* Wi1   = (const float*)d_in[5];
    const float* bi1   = (const float*)d_in[6];
    const float* Wi2   = (const float*)d_in[7];
    const float* bi2   = (const float*)d_in[8];
    const float* Wd1   = (const float*)d_in[9];
    const float* bd1   = (const float*)d_in[10];
    const float* Wd2   = (const float*)d_in[11];
    const float* bd2   = (const float*)d_in[12];
    float* outp = (float*)d_out;

    char* ws = (char*)d_ws;
    float* P     = (float*)ws;                        // 6291456 B
    float* At    = (float*)(ws + 6291456);            // 2048 B
    float* Ct    = (float*)(ws + 6293504);            // 2048 B
    float* W2m2t = (float*)(ws + 6295552);            // 2048 B

    k_gemm<<<257, 512, 0, stream>>>(b_i_n, U0, U1, U2, Wi1, bi1, Wd1, bd1, Wd2,
                                    P, At, Ct, W2m2t);
    k_rk4<<<NB / 4, 256, 0, stream>>>(b_t_n, At, Ct, W2m2t, Wi2, bi2, bd2,
                                      P, outp);
}